// Round 1
// baseline (2358.892 us; speedup 1.0000x reference)
//
#include <hip/hip_runtime.h>

typedef float v2f __attribute__((ext_vector_type(2)));
typedef float v4f __attribute__((ext_vector_type(4)));

#define FMA2(a, b, c) __builtin_elementwise_fma((a), (b), (c))

// Problem constants
// x1: (32768, 16, 64), x2: (32768, 16, 32), w: (32768, 64, 32)
// A,B,C: (16, 64); out: (32768, 16, 64)
constexpr int ITERS = 4;   // batches per wave per block pass
constexpr int T2S   = 36;  // padded row stride (floats) for t2 in LDS; 144B = 16B-aligned

__global__ __launch_bounds__(256, 2)
void cp_tp_kernel(const float* __restrict__ x1g, const float* __restrict__ x2g,
                  const float* __restrict__ wg,  const float* __restrict__ Ag,
                  const float* __restrict__ Bg,  const float* __restrict__ Cg,
                  float* __restrict__ outg)
{
    __shared__ float A_s[16 * 64];       // row-major [i][r]
    __shared__ float Ct_s[64 * 16];      // transposed C: [r][c]
    __shared__ float x2_s[4][16 * 32];   // per-wave x2 tile
    __shared__ float t2_s[4][64 * T2S];  // per-wave t2, padded rows

    const int tid  = threadIdx.x;
    const int wv   = tid >> 6;
    const int lane = tid & 63;

    // Stage A (row-major) and C (transposed) once per block.
    for (int k = tid; k < 1024; k += 256) {
        A_s[k] = Ag[k];
        int c = k >> 6, r = k & 63;
        Ct_s[r * 16 + c] = Cg[k];
    }

    // B column for this lane (batch-invariant): B[j][lane]
    float bcol[16];
#pragma unroll
    for (int j = 0; j < 16; ++j) bcol[j] = Bg[j * 64 + lane];

    __syncthreads();

    for (int it = 0; it < ITERS; ++it) {
        const int b = (blockIdx.x * ITERS + it) * 4 + wv;
        const float* x1b = x1g + (size_t)b * 1024;
        const float* x2b = x2g + (size_t)b * 512;
        const float* wb  = wg  + (size_t)b * 2048;

        // ---- stage x2 tile into LDS (coalesced) ----
        {
            const v4f* src = (const v4f*)x2b;
            v4f* dst = (v4f*)x2_s[wv];
            dst[lane]      = src[lane];
            dst[lane + 64] = src[lane + 64];
        }

        // ---- w row for this lane: w[b][lane][0..31] ----
        v4f wq[8];
        {
            const v4f* wp = (const v4f*)(wb + lane * 32);
#pragma unroll
            for (int k = 0; k < 8; ++k) wq[k] = wp[k];
        }

        // ---- x1 column o=lane (coalesced, stride 64) ----
        float xr[16];
#pragma unroll
        for (int i = 0; i < 16; ++i) xr[i] = x1b[i * 64 + lane];

        // ---- t1[r] = sum_i x1[i,lane] * A[i,r], kept as 32 float2 ----
        v2f t1v[32];
#pragma unroll
        for (int rp = 0; rp < 32; ++rp) t1v[rp] = v2f{0.f, 0.f};
#pragma unroll
        for (int i = 0; i < 16; ++i) {
            v2f xv = {xr[i], xr[i]};
            const v4f* arow = (const v4f*)(A_s + i * 64);
#pragma unroll
            for (int r4 = 0; r4 < 16; ++r4) {
                v4f a4 = arow[r4];
                v2f alo = {a4.x, a4.y}, ahi = {a4.z, a4.w};
                t1v[2 * r4]     = FMA2(xv, alo, t1v[2 * r4]);
                t1v[2 * r4 + 1] = FMA2(xv, ahi, t1v[2 * r4 + 1]);
            }
        }

        __syncthreads();  // x2_s ready

        // ---- t2 row r=lane: t2[lane,v] = sum_j x2[j,v] * B[j,lane] ----
        {
            v2f acc[16];
#pragma unroll
            for (int vp = 0; vp < 16; ++vp) acc[vp] = v2f{0.f, 0.f};
#pragma unroll
            for (int j = 0; j < 16; ++j) {
                v2f bv = {bcol[j], bcol[j]};
                const v4f* xrow = (const v4f*)(x2_s[wv] + j * 32);
#pragma unroll
                for (int v4 = 0; v4 < 8; ++v4) {
                    v4f xq = xrow[v4];
                    v2f xlo = {xq.x, xq.y}, xhi = {xq.z, xq.w};
                    acc[2 * v4]     = FMA2(bv, xlo, acc[2 * v4]);
                    acc[2 * v4 + 1] = FMA2(bv, xhi, acc[2 * v4 + 1]);
                }
            }
            v4f* dst = (v4f*)(t2_s[wv] + lane * T2S);
#pragma unroll
            for (int k = 0; k < 8; ++k) {
                v4f q = {acc[2 * k].x, acc[2 * k].y, acc[2 * k + 1].x, acc[2 * k + 1].y};
                dst[k] = q;
            }
        }

        __syncthreads();  // t2_s ready

        // ---- fused t3 + output accumulation ----
        // t3[r,lane] = sum_v t2[r,v] * w[lane,v]; p = t1[r]*t3;
        // out[c,lane] += C[c,r]*p  (Ct_s row r is contiguous in c)
        v2f outv[8];
#pragma unroll
        for (int cp = 0; cp < 8; ++cp) outv[cp] = v2f{0.f, 0.f};

#pragma unroll
        for (int r = 0; r < 64; ++r) {
            const v4f* t2r = (const v4f*)(t2_s[wv] + r * T2S);
            v2f acc = v2f{0.f, 0.f};
#pragma unroll
            for (int k = 0; k < 8; ++k) {
                v4f q = t2r[k];
                v2f qlo = {q.x, q.y}, qhi = {q.z, q.w};
                v2f wlo = {wq[k].x, wq[k].y}, whi = {wq[k].z, wq[k].w};
                acc = FMA2(qlo, wlo, acc);
                acc = FMA2(qhi, whi, acc);
            }
            float t3  = acc.x + acc.y;
            float t1r = (r & 1) ? t1v[r >> 1].y : t1v[r >> 1].x;
            float p   = t1r * t3;
            v2f pv = {p, p};
            const v4f* ctr = (const v4f*)(Ct_s + r * 16);
#pragma unroll
            for (int c4 = 0; c4 < 4; ++c4) {
                v4f cq = ctr[c4];
                v2f clo = {cq.x, cq.y}, chi = {cq.z, cq.w};
                outv[2 * c4]     = FMA2(pv, clo, outv[2 * c4]);
                outv[2 * c4 + 1] = FMA2(pv, chi, outv[2 * c4 + 1]);
            }
        }

        // ---- store out[b, c, lane] (coalesced per c) ----
        float* ob = outg + (size_t)b * 1024;
#pragma unroll
        for (int c = 0; c < 16; ++c) {
            float v = (c & 1) ? outv[c >> 1].y : outv[c >> 1].x;
            ob[c * 64 + lane] = v;
        }

        __syncthreads();  // protect x2_s/t2_s WAR before next iteration
    }
}

extern "C" void kernel_launch(void* const* d_in, const int* in_sizes, int n_in,
                              void* d_out, int out_size, void* d_ws, size_t ws_size,
                              hipStream_t stream) {
    const float* x1 = (const float*)d_in[0];
    const float* x2 = (const float*)d_in[1];
    const float* w  = (const float*)d_in[2];
    const float* A  = (const float*)d_in[3];
    const float* B  = (const float*)d_in[4];
    const float* C  = (const float*)d_in[5];
    float* out = (float*)d_out;

    // 2048 blocks * 4 iters * 4 waves/block = 32768 batches
    cp_tp_kernel<<<dim3(2048), dim3(256), 0, stream>>>(x1, x2, w, A, B, C, out);
}